// Round 7
// baseline (181.381 us; speedup 1.0000x reference)
//
#include <hip/hip_runtime.h>
#include <math.h>
#include <limits.h>

#define EPS  1e-9f
#define TOPK 5

typedef float v4f __attribute__((ext_vector_type(4)));

// strict total order: higher val wins; on equal val, lower index wins
__device__ __forceinline__ bool better(float av, int ai, float bv, int bi) {
    return (av > bv) || (av == bv && ai < bi);
}

// insert (v,idx) into desc-sorted top-TOPK register arrays.
// Fully unrolled, all indices compile-time after unroll (no scratch).
__device__ __forceinline__ void insert_top(float sv[TOPK], int si[TOPK], float v, int idx) {
    if (!better(v, idx, sv[TOPK - 1], si[TOPK - 1])) return;
    sv[TOPK - 1] = v; si[TOPK - 1] = idx;
#pragma unroll
    for (int j = TOPK - 1; j > 0; --j) {
        if (better(sv[j], si[j], sv[j - 1], si[j - 1])) {
            float tv = sv[j]; sv[j] = sv[j - 1]; sv[j - 1] = tv;
            int   ti = si[j]; si[j] = si[j - 1]; si[j - 1] = ti;
        }
    }
}

__device__ __forceinline__ float dot4(v4f a, v4f b) {
    return a.x * b.x + a.y * b.y + a.z * b.z + a.w * b.w;
}

#define NTLOAD(p) __builtin_nontemporal_load(p)

// ---------------------------------------------------------------------------
// Single fused kernel (R3 streaming body + last-block final reduce):
//  - one wave per row-PAIR (8 NT float4 loads in flight, contiguous 8 KB
//    stream); psi in 16 VGPRs; dot+nrm butterfly; lane-0 top-5 insert.
//  - each block writes 5 (val,idx) candidates, __threadfence(), atomicAdd
//    on a completion counter; the LAST block re-reduces all NC candidates
//    with 256 threads and writes d_out. No second kernel launch, no full
//    drain between stream and reduce. Assumes D == 1024.
// ---------------------------------------------------------------------------
__global__ __launch_bounds__(256) void sim_top_kernel(const v4f* __restrict__ vocab,
                                                      const v4f* __restrict__ psi4,
                                                      float* __restrict__ cand_v,
                                                      int* __restrict__ cand_i,
                                                      unsigned int* __restrict__ counter,
                                                      int V, int K,
                                                      float* __restrict__ out) {
    __shared__ float wvs[4 * TOPK];
    __shared__ int   wis[4 * TOPK];
    __shared__ int   s_last;
    const int tid  = threadIdx.x;
    const int lane = tid & 63;
    const int wave = tid >> 6;
    const int wavesPerBlock = blockDim.x >> 6;
    const int gwave  = blockIdx.x * wavesPerBlock + wave;
    const int nwaves = gridDim.x * wavesPerBlock;
    const int NC = gridDim.x * TOPK;

    // psi fragments in registers: 64 lanes x 4 chunks = all 256 float4 of psi.
    const v4f p0 = psi4[lane];
    const v4f p1 = psi4[64 + lane];
    const v4f p2 = psi4[128 + lane];
    const v4f p3 = psi4[192 + lane];

    // wave-redundant ||psi||^2 -> scale (identical add order in every wave)
    float ps = dot4(p0, p0) + dot4(p1, p1) + dot4(p2, p2) + dot4(p3, p3);
    for (int off = 32; off > 0; off >>= 1) ps += __shfl_xor(ps, off);
    const float scale = 1.0f / (sqrtf(ps) + EPS);

    float tv[TOPK]; int ti[TOPK];
#pragma unroll
    for (int j = 0; j < TOPK; ++j) { tv[j] = -INFINITY; ti[j] = INT_MAX; }

    const int NP = V >> 1;  // contiguous row pairs
    for (int p = gwave; p < NP; p += nwaves) {
        const v4f* ra = vocab + (size_t)(2 * p) * 256;
        v4f a0 = NTLOAD(ra + lane);
        v4f a1 = NTLOAD(ra + 64 + lane);
        v4f a2 = NTLOAD(ra + 128 + lane);
        v4f a3 = NTLOAD(ra + 192 + lane);
        v4f b0 = NTLOAD(ra + 256 + lane);
        v4f b1 = NTLOAD(ra + 320 + lane);
        v4f b2 = NTLOAD(ra + 384 + lane);
        v4f b3 = NTLOAD(ra + 448 + lane);

        float dotA = dot4(a0, p0) + dot4(a1, p1) + dot4(a2, p2) + dot4(a3, p3);
        float nrmA = dot4(a0, a0) + dot4(a1, a1) + dot4(a2, a2) + dot4(a3, a3);
        float dotB = dot4(b0, p0) + dot4(b1, p1) + dot4(b2, p2) + dot4(b3, p3);
        float nrmB = dot4(b0, b0) + dot4(b1, b1) + dot4(b2, b2) + dot4(b3, b3);

        for (int off = 32; off > 0; off >>= 1) {
            dotA += __shfl_xor(dotA, off);
            nrmA += __shfl_xor(nrmA, off);
            dotB += __shfl_xor(dotB, off);
            nrmB += __shfl_xor(nrmB, off);
        }
        if (lane == 0) {
            insert_top(tv, ti, dotA * scale / (sqrtf(nrmA) + EPS), 2 * p);
            insert_top(tv, ti, dotB * scale / (sqrtf(nrmB) + EPS), 2 * p + 1);
        }
    }

    // odd-V tail (not hit for V=128000)
    if ((V & 1) && gwave == 0) {
        const int row = V - 1;
        const v4f* ra = vocab + (size_t)row * 256;
        v4f a0 = ra[lane], a1 = ra[64 + lane], a2 = ra[128 + lane], a3 = ra[192 + lane];
        float dotA = dot4(a0, p0) + dot4(a1, p1) + dot4(a2, p2) + dot4(a3, p3);
        float nrmA = dot4(a0, a0) + dot4(a1, a1) + dot4(a2, a2) + dot4(a3, a3);
        for (int off = 32; off > 0; off >>= 1) {
            dotA += __shfl_xor(dotA, off);
            nrmA += __shfl_xor(nrmA, off);
        }
        if (lane == 0) insert_top(tv, ti, dotA * scale / (sqrtf(nrmA) + EPS), row);
    }

    if (lane == 0) {
#pragma unroll
        for (int j = 0; j < TOPK; ++j) { wvs[wave * TOPK + j] = tv[j]; wis[wave * TOPK + j] = ti[j]; }
    }
    __syncthreads();
    if (tid == 0) {
        float bv[TOPK]; int bi[TOPK];
#pragma unroll
        for (int j = 0; j < TOPK; ++j) { bv[j] = -INFINITY; bi[j] = INT_MAX; }
        for (int e = 0; e < wavesPerBlock * TOPK; ++e) insert_top(bv, bi, wvs[e], wis[e]);
#pragma unroll
        for (int j = 0; j < TOPK; ++j) {
            cand_v[blockIdx.x * TOPK + j] = bv[j];
            cand_i[blockIdx.x * TOPK + j] = bi[j];
        }
        // release: make candidate writes visible device-wide, then signal
        __threadfence();
        unsigned int prev = atomicAdd(counter, 1u);
        s_last = (prev == (unsigned int)(gridDim.x - 1)) ? 1 : 0;
    }
    __syncthreads();

    if (s_last) {
        // acquire: all blocks signaled -> all candidate writes visible
        __threadfence();
        float sv[TOPK]; int si[TOPK];
#pragma unroll
        for (int j = 0; j < TOPK; ++j) { sv[j] = -INFINITY; si[j] = INT_MAX; }
        for (int i = tid; i < NC; i += blockDim.x)
            insert_top(sv, si, cand_v[i], cand_i[i]);

        for (int step = 1; step < 64; step <<= 1) {
            float ov[TOPK]; int oi[TOPK];
#pragma unroll
            for (int j = 0; j < TOPK; ++j) {
                ov[j] = __shfl_xor(sv[j], step);
                oi[j] = __shfl_xor(si[j], step);
            }
#pragma unroll
            for (int j = 0; j < TOPK; ++j) insert_top(sv, si, ov[j], oi[j]);
        }

        if (lane == 0) {
#pragma unroll
            for (int j = 0; j < TOPK; ++j) { wvs[wave * TOPK + j] = sv[j]; wis[wave * TOPK + j] = si[j]; }
        }
        __syncthreads();
        if (tid == 0) {
            float bv[TOPK]; int bi[TOPK];
#pragma unroll
            for (int j = 0; j < TOPK; ++j) { bv[j] = -INFINITY; bi[j] = INT_MAX; }
            for (int e = 0; e < wavesPerBlock * TOPK; ++e) insert_top(bv, bi, wvs[e], wis[e]);
            for (int k = 0; k < K && k < TOPK; ++k) {
                out[k]     = bv[k];
                out[K + k] = (float)bi[k];
            }
        }
    }
}

extern "C" void kernel_launch(void* const* d_in, const int* in_sizes, int n_in,
                              void* d_out, int out_size, void* d_ws, size_t ws_size,
                              hipStream_t stream) {
    const float* psi   = (const float*)d_in[0];
    const float* vocab = (const float*)d_in[1];
    const int D = in_sizes[0];           // 1024 (kernel assumes this)
    const int V = in_sizes[1] / D;       // 128000
    const int K = out_size / 2;          // 5
    (void)D;

    // 2000 blocks -> 8000 waves; 64000 row-pairs / 8000 = exactly 8 pairs/wave
    const int blocks = 2000;
    const int NC = blocks * TOPK;        // 10000 candidates

    float*        cand_v  = (float*)d_ws;
    int*          cand_i  = (int*)((float*)d_ws + NC);
    unsigned int* counter = (unsigned int*)(cand_i + NC);

    // zero the completion counter each launch (graph-capturable stream op)
    hipMemsetAsync(counter, 0, sizeof(unsigned int), stream);

    sim_top_kernel<<<blocks, 256, 0, stream>>>((const v4f*)vocab, (const v4f*)psi,
                                               cand_v, cand_i, counter, V, K,
                                               (float*)d_out);
}

// Round 8
// 129.331 us; speedup vs baseline: 1.4025x; 1.4025x over previous
//
#include <hip/hip_runtime.h>
#include <math.h>
#include <limits.h>

#define EPS  1e-9f
#define TOPK 5

// strict total order: higher val wins; on equal val, lower index wins
__device__ __forceinline__ bool better(float av, int ai, float bv, int bi) {
    return (av > bv) || (av == bv && ai < bi);
}

// insert (v,idx) into desc-sorted top-TOPK register arrays.
// Fully unrolled, all indices compile-time after unroll (no scratch).
__device__ __forceinline__ void insert_top(float sv[TOPK], int si[TOPK], float v, int idx) {
    if (!better(v, idx, sv[TOPK - 1], si[TOPK - 1])) return;
    sv[TOPK - 1] = v; si[TOPK - 1] = idx;
#pragma unroll
    for (int j = TOPK - 1; j > 0; --j) {
        if (better(sv[j], si[j], sv[j - 1], si[j - 1])) {
            float tv = sv[j]; sv[j] = sv[j - 1]; sv[j - 1] = tv;
            int   ti = si[j]; si[j] = si[j - 1]; si[j - 1] = ti;
        }
    }
}

// ---------------------------------------------------------------------------
// K1: R1's proven stream body. One wave per row (grid-stride), LDS psi,
// plain cached float4 loads, dot+nrm fused single pass, sims[] written by
// lane 0. psi scale computed in-kernel (wave-redundant, identical add order
// in every wave -> deterministic). Slim wave context -> max occupancy.
// Assumes D % 256 == 0 (D = 1024 here).
// ---------------------------------------------------------------------------
__global__ __launch_bounds__(256) void sim_kernel(const float4* __restrict__ vocab,
                                                  const float4* __restrict__ psi4,
                                                  float* __restrict__ sims,
                                                  int V, int D) {
    __shared__ float4 psi_lds[256];  // up to D = 1024 floats
    const int tid = threadIdx.x;
    const int D4 = D >> 2;           // 256 for D=1024
    for (int i = tid; i < D4; i += blockDim.x) psi_lds[i] = psi4[i];
    __syncthreads();

    const int lane = tid & 63;
    const int wave = tid >> 6;
    const int wavesPerBlock = blockDim.x >> 6;
    const int gwave  = blockIdx.x * wavesPerBlock + wave;
    const int nwaves = gridDim.x * wavesPerBlock;
    const int iters  = D4 >> 6;      // float4-chunks per lane (4 for D=1024)

    // wave-redundant ||psi||^2 from LDS -> scale (same add order every wave)
    float ps = 0.f;
#pragma unroll 4
    for (int it = 0; it < iters; ++it) {
        float4 p = psi_lds[it * 64 + lane];
        ps += p.x * p.x + p.y * p.y + p.z * p.z + p.w * p.w;
    }
    for (int off = 32; off > 0; off >>= 1) ps += __shfl_xor(ps, off);
    const float scale = 1.0f / (sqrtf(ps) + EPS);

    for (int row = gwave; row < V; row += nwaves) {
        const float4* rp = vocab + (size_t)row * D4;
        float dot = 0.f, nrm = 0.f;
#pragma unroll 4
        for (int it = 0; it < iters; ++it) {
            float4 a = rp[it * 64 + lane];
            float4 p = psi_lds[it * 64 + lane];
            dot += a.x * p.x + a.y * p.y + a.z * p.z + a.w * p.w;
            nrm += a.x * a.x + a.y * a.y + a.z * a.z + a.w * a.w;
        }
        for (int off = 32; off > 0; off >>= 1) {
            dot += __shfl_xor(dot, off);
            nrm += __shfl_xor(nrm, off);
        }
        if (lane == 0) sims[row] = dot * scale / (sqrtf(nrm) + EPS);
    }
}

// ---------------------------------------------------------------------------
// K2: parallel top-k stage 1. 256 blocks x 256 threads scan sims (coalesced
// strided); per-thread register top-5 -> wave butterfly merge -> LDS ->
// thread-0 block merge -> 5 candidates per block.
// ---------------------------------------------------------------------------
__global__ __launch_bounds__(256) void topk_stage1(const float* __restrict__ sims,
                                                   int V,
                                                   float* __restrict__ cand_v,
                                                   int* __restrict__ cand_i) {
    __shared__ float wvs[4 * TOPK];
    __shared__ int   wis[4 * TOPK];
    const int tid = threadIdx.x;
    const int lane = tid & 63, wave = tid >> 6;
    const int wavesPerBlock = blockDim.x >> 6;
    const int gtid = blockIdx.x * blockDim.x + tid;
    const int nthr = gridDim.x * blockDim.x;

    float sv[TOPK]; int si[TOPK];
#pragma unroll
    for (int j = 0; j < TOPK; ++j) { sv[j] = -INFINITY; si[j] = INT_MAX; }

    for (int i = gtid; i < V; i += nthr) insert_top(sv, si, sims[i], i);

    for (int step = 1; step < 64; step <<= 1) {
        float ov[TOPK]; int oi[TOPK];
#pragma unroll
        for (int j = 0; j < TOPK; ++j) {
            ov[j] = __shfl_xor(sv[j], step);
            oi[j] = __shfl_xor(si[j], step);
        }
#pragma unroll
        for (int j = 0; j < TOPK; ++j) insert_top(sv, si, ov[j], oi[j]);
    }

    if (lane == 0) {
#pragma unroll
        for (int j = 0; j < TOPK; ++j) { wvs[wave * TOPK + j] = sv[j]; wis[wave * TOPK + j] = si[j]; }
    }
    __syncthreads();
    if (tid == 0) {
        float bv[TOPK]; int bi[TOPK];
#pragma unroll
        for (int j = 0; j < TOPK; ++j) { bv[j] = -INFINITY; bi[j] = INT_MAX; }
        for (int e = 0; e < wavesPerBlock * TOPK; ++e) insert_top(bv, bi, wvs[e], wis[e]);
#pragma unroll
        for (int j = 0; j < TOPK; ++j) {
            cand_v[blockIdx.x * TOPK + j] = bv[j];
            cand_i[blockIdx.x * TOPK + j] = bi[j];
        }
    }
}

// ---------------------------------------------------------------------------
// K3: final reduce of NC candidates -> top-K. 1 block x 256 threads.
// out[0..K-1] = scores, out[K..2K-1] = indices (as float).
// ---------------------------------------------------------------------------
__global__ __launch_bounds__(256) void topk_final(const float* __restrict__ cand_v,
                                                  const int* __restrict__ cand_i,
                                                  int NC, int K,
                                                  float* __restrict__ out) {
    __shared__ float wvs[4 * TOPK];
    __shared__ int   wis[4 * TOPK];
    const int tid = threadIdx.x;
    const int lane = tid & 63, wave = tid >> 6;
    const int nwaves = blockDim.x >> 6;

    float sv[TOPK]; int si[TOPK];
#pragma unroll
    for (int j = 0; j < TOPK; ++j) { sv[j] = -INFINITY; si[j] = INT_MAX; }

    for (int i = tid; i < NC; i += blockDim.x) insert_top(sv, si, cand_v[i], cand_i[i]);

    for (int step = 1; step < 64; step <<= 1) {
        float ov[TOPK]; int oi[TOPK];
#pragma unroll
        for (int j = 0; j < TOPK; ++j) {
            ov[j] = __shfl_xor(sv[j], step);
            oi[j] = __shfl_xor(si[j], step);
        }
#pragma unroll
        for (int j = 0; j < TOPK; ++j) insert_top(sv, si, ov[j], oi[j]);
    }

    if (lane == 0) {
#pragma unroll
        for (int j = 0; j < TOPK; ++j) { wvs[wave * TOPK + j] = sv[j]; wis[wave * TOPK + j] = si[j]; }
    }
    __syncthreads();
    if (tid == 0) {
        float bv[TOPK]; int bi[TOPK];
#pragma unroll
        for (int j = 0; j < TOPK; ++j) { bv[j] = -INFINITY; bi[j] = INT_MAX; }
        for (int e = 0; e < nwaves * TOPK; ++e) insert_top(bv, bi, wvs[e], wis[e]);
        for (int k = 0; k < K && k < TOPK; ++k) {
            out[k]     = bv[k];
            out[K + k] = (float)bi[k];
        }
    }
}

extern "C" void kernel_launch(void* const* d_in, const int* in_sizes, int n_in,
                              void* d_out, int out_size, void* d_ws, size_t ws_size,
                              hipStream_t stream) {
    const float* psi   = (const float*)d_in[0];
    const float* vocab = (const float*)d_in[1];
    const int D = in_sizes[0];           // 1024
    const int V = in_sizes[1] / D;       // 128000
    const int K = out_size / 2;          // 5

    const int blocks1 = 2048;            // K1: proven-fastest stream config
    const int blocks2 = 256;             // K2: one fast pass over sims
    const int NC = blocks2 * TOPK;       // 1280 candidates

    float* ws     = (float*)d_ws;
    float* sims   = ws;                          // V floats
    float* cand_v = ws + V;                      // NC floats
    int*   cand_i = (int*)(ws + V + NC);         // NC ints

    sim_kernel<<<blocks1, 256, 0, stream>>>((const float4*)vocab, (const float4*)psi,
                                            sims, V, D);

    topk_stage1<<<blocks2, 256, 0, stream>>>(sims, V, cand_v, cand_i);

    topk_final<<<1, 256, 0, stream>>>(cand_v, cand_i, NC, K, (float*)d_out);
}

// Round 9
// 122.508 us; speedup vs baseline: 1.4806x; 1.0557x over previous
//
#include <hip/hip_runtime.h>
#include <math.h>
#include <limits.h>

#define EPS  1e-9f
#define TOPK 5

typedef float v4f __attribute__((ext_vector_type(4)));

// strict total order: higher val wins; on equal val, lower index wins
__device__ __forceinline__ bool better(float av, int ai, float bv, int bi) {
    return (av > bv) || (av == bv && ai < bi);
}

// insert (v,idx) into desc-sorted top-TOPK register arrays.
// Fully unrolled, all indices compile-time after unroll (no scratch).
__device__ __forceinline__ void insert_top(float sv[TOPK], int si[TOPK], float v, int idx) {
    if (!better(v, idx, sv[TOPK - 1], si[TOPK - 1])) return;
    sv[TOPK - 1] = v; si[TOPK - 1] = idx;
#pragma unroll
    for (int j = TOPK - 1; j > 0; --j) {
        if (better(sv[j], si[j], sv[j - 1], si[j - 1])) {
            float tv = sv[j]; sv[j] = sv[j - 1]; sv[j - 1] = tv;
            int   ti = si[j]; si[j] = si[j - 1]; si[j - 1] = ti;
        }
    }
}

__device__ __forceinline__ float dot4(v4f a, v4f b) {
    return a.x * b.x + a.y * b.y + a.z * b.z + a.w * b.w;
}

#define NTLOAD(p) __builtin_nontemporal_load(p)

// ---------------------------------------------------------------------------
// R3's proven fused stream (NT loads, pair/wave, reg-psi, lane-0 insert),
// with ONE change: each wave owns a CONTIGUOUS run of 8 row-pairs (64 KB
// sequential stream -> DRAM page locality) instead of grid-striding pairs
// 64 MB apart. No __launch_bounds__ cap (R6's spill trap). D == 1024.
// ---------------------------------------------------------------------------
__global__ __launch_bounds__(256) void sim_top_kernel(const v4f* __restrict__ vocab,
                                                      const v4f* __restrict__ psi4,
                                                      float* __restrict__ cand_v,
                                                      int* __restrict__ cand_i,
                                                      int V) {
    __shared__ float wvs[4 * TOPK];
    __shared__ int   wis[4 * TOPK];
    const int tid  = threadIdx.x;
    const int lane = tid & 63;
    const int wave = tid >> 6;
    const int wavesPerBlock = blockDim.x >> 6;
    const int gwave = blockIdx.x * wavesPerBlock + wave;
    const int NW    = gridDim.x * wavesPerBlock;

    // psi fragments in registers: 64 lanes x 4 chunks = all 256 float4 of psi.
    const v4f p0 = psi4[lane];
    const v4f p1 = psi4[64 + lane];
    const v4f p2 = psi4[128 + lane];
    const v4f p3 = psi4[192 + lane];

    // wave-redundant ||psi||^2 -> scale (identical add order in every wave)
    float ps = dot4(p0, p0) + dot4(p1, p1) + dot4(p2, p2) + dot4(p3, p3);
    for (int off = 32; off > 0; off >>= 1) ps += __shfl_xor(ps, off);
    const float scale = 1.0f / (sqrtf(ps) + EPS);

    float tv[TOPK]; int ti[TOPK];
#pragma unroll
    for (int j = 0; j < TOPK; ++j) { tv[j] = -INFINITY; ti[j] = INT_MAX; }

    // contiguous balanced split of row-pairs: wave owns [start, start+cnt)
    const int NP  = V >> 1;                 // 64000 pairs
    const int per = NP / NW;                // 8 for V=128000, NW=8000
    const int rem = NP % NW;                // 0
    const int start = gwave * per + (gwave < rem ? gwave : rem);
    const int cnt   = per + (gwave < rem ? 1 : 0);

    for (int k = 0; k < cnt; ++k) {
        const int p = start + k;
        const v4f* ra = vocab + (size_t)(2 * p) * 256;
        v4f a0 = NTLOAD(ra + lane);
        v4f a1 = NTLOAD(ra + 64 + lane);
        v4f a2 = NTLOAD(ra + 128 + lane);
        v4f a3 = NTLOAD(ra + 192 + lane);
        v4f b0 = NTLOAD(ra + 256 + lane);
        v4f b1 = NTLOAD(ra + 320 + lane);
        v4f b2 = NTLOAD(ra + 384 + lane);
        v4f b3 = NTLOAD(ra + 448 + lane);

        float dotA = dot4(a0, p0) + dot4(a1, p1) + dot4(a2, p2) + dot4(a3, p3);
        float nrmA = dot4(a0, a0) + dot4(a1, a1) + dot4(a2, a2) + dot4(a3, a3);
        float dotB = dot4(b0, p0) + dot4(b1, p1) + dot4(b2, p2) + dot4(b3, p3);
        float nrmB = dot4(b0, b0) + dot4(b1, b1) + dot4(b2, b2) + dot4(b3, b3);

        for (int off = 32; off > 0; off >>= 1) {
            dotA += __shfl_xor(dotA, off);
            nrmA += __shfl_xor(nrmA, off);
            dotB += __shfl_xor(dotB, off);
            nrmB += __shfl_xor(nrmB, off);
        }
        if (lane == 0) {
            insert_top(tv, ti, dotA * scale / (sqrtf(nrmA) + EPS), 2 * p);
            insert_top(tv, ti, dotB * scale / (sqrtf(nrmB) + EPS), 2 * p + 1);
        }
    }

    // odd-V tail (not hit for V=128000)
    if ((V & 1) && gwave == 0) {
        const int row = V - 1;
        const v4f* ra = vocab + (size_t)row * 256;
        v4f a0 = ra[lane], a1 = ra[64 + lane], a2 = ra[128 + lane], a3 = ra[192 + lane];
        float dotA = dot4(a0, p0) + dot4(a1, p1) + dot4(a2, p2) + dot4(a3, p3);
        float nrmA = dot4(a0, a0) + dot4(a1, a1) + dot4(a2, a2) + dot4(a3, a3);
        for (int off = 32; off > 0; off >>= 1) {
            dotA += __shfl_xor(dotA, off);
            nrmA += __shfl_xor(nrmA, off);
        }
        if (lane == 0) insert_top(tv, ti, dotA * scale / (sqrtf(nrmA) + EPS), row);
    }

    if (lane == 0) {
#pragma unroll
        for (int j = 0; j < TOPK; ++j) { wvs[wave * TOPK + j] = tv[j]; wis[wave * TOPK + j] = ti[j]; }
    }
    __syncthreads();
    if (tid == 0) {
        float bv[TOPK]; int bi[TOPK];
#pragma unroll
        for (int j = 0; j < TOPK; ++j) { bv[j] = -INFINITY; bi[j] = INT_MAX; }
        for (int e = 0; e < wavesPerBlock * TOPK; ++e) insert_top(bv, bi, wvs[e], wis[e]);
#pragma unroll
        for (int j = 0; j < TOPK; ++j) {
            cand_v[blockIdx.x * TOPK + j] = bv[j];
            cand_i[blockIdx.x * TOPK + j] = bi[j];
        }
    }
}

// ---------------------------------------------------------------------------
// Reduce NC candidates -> global top-K. Single block; per-thread register
// top-5 -> wave butterfly merge -> LDS -> thread-0 final merge.
// out[0..K-1] = scores, out[K..2K-1] = indices (as float).
// ---------------------------------------------------------------------------
__global__ __launch_bounds__(1024) void topk_reduce_kernel(const float* __restrict__ cand_v,
                                                           const int* __restrict__ cand_i,
                                                           int NC, int K,
                                                           float* __restrict__ out) {
    __shared__ float wvs[16 * TOPK];
    __shared__ int   wis[16 * TOPK];
    const int tid = threadIdx.x;
    const int lane = tid & 63, wave = tid >> 6;
    const int nwaves = blockDim.x >> 6;

    float sv[TOPK]; int si[TOPK];
#pragma unroll
    for (int j = 0; j < TOPK; ++j) { sv[j] = -INFINITY; si[j] = INT_MAX; }

    for (int i = tid; i < NC; i += blockDim.x) insert_top(sv, si, cand_v[i], cand_i[i]);

    for (int step = 1; step < 64; step <<= 1) {
        float ov[TOPK]; int oi[TOPK];
#pragma unroll
        for (int j = 0; j < TOPK; ++j) {
            ov[j] = __shfl_xor(sv[j], step);
            oi[j] = __shfl_xor(si[j], step);
        }
#pragma unroll
        for (int j = 0; j < TOPK; ++j) insert_top(sv, si, ov[j], oi[j]);
    }

    if (lane == 0) {
#pragma unroll
        for (int j = 0; j < TOPK; ++j) { wvs[wave * TOPK + j] = sv[j]; wis[wave * TOPK + j] = si[j]; }
    }
    __syncthreads();
    if (tid == 0) {
        float bv[TOPK]; int bi[TOPK];
#pragma unroll
        for (int j = 0; j < TOPK; ++j) { bv[j] = -INFINITY; bi[j] = INT_MAX; }
        for (int e = 0; e < nwaves * TOPK; ++e) insert_top(bv, bi, wvs[e], wis[e]);
        for (int k = 0; k < K && k < TOPK; ++k) {
            out[k]     = bv[k];
            out[K + k] = (float)bi[k];
        }
    }
}

extern "C" void kernel_launch(void* const* d_in, const int* in_sizes, int n_in,
                              void* d_out, int out_size, void* d_ws, size_t ws_size,
                              hipStream_t stream) {
    const float* psi   = (const float*)d_in[0];
    const float* vocab = (const float*)d_in[1];
    const int D = in_sizes[0];           // 1024 (kernel assumes this)
    const int V = in_sizes[1] / D;       // 128000
    const int K = out_size / 2;          // 5
    (void)D;

    // 2000 blocks -> 8000 waves; 64000 pairs / 8000 = exactly 8 pairs/wave
    const int blocks = 2000;
    const int NC = blocks * TOPK;        // 10000 candidates

    float* cand_v = (float*)d_ws;
    int*   cand_i = (int*)((float*)d_ws + NC);

    sim_top_kernel<<<blocks, 256, 0, stream>>>((const v4f*)vocab, (const v4f*)psi,
                                               cand_v, cand_i, V);

    topk_reduce_kernel<<<1, 1024, 0, stream>>>(cand_v, cand_i, NC, K, (float*)d_out);
}

// Round 10
// 117.518 us; speedup vs baseline: 1.5434x; 1.0425x over previous
//
#include <hip/hip_runtime.h>
#include <math.h>
#include <limits.h>

#define EPS  1e-9f
#define TOPK 5

typedef float v4f __attribute__((ext_vector_type(4)));

// strict total order: higher val wins; on equal val, lower index wins
__device__ __forceinline__ bool better(float av, int ai, float bv, int bi) {
    return (av > bv) || (av == bv && ai < bi);
}

// insert (v,idx) into desc-sorted top-TOPK register arrays.
// Fully unrolled, all indices compile-time after unroll (no scratch).
__device__ __forceinline__ void insert_top(float sv[TOPK], int si[TOPK], float v, int idx) {
    if (!better(v, idx, sv[TOPK - 1], si[TOPK - 1])) return;
    sv[TOPK - 1] = v; si[TOPK - 1] = idx;
#pragma unroll
    for (int j = TOPK - 1; j > 0; --j) {
        if (better(sv[j], si[j], sv[j - 1], si[j - 1])) {
            float tv = sv[j]; sv[j] = sv[j - 1]; sv[j - 1] = tv;
            int   ti = si[j]; si[j] = si[j - 1]; si[j - 1] = ti;
        }
    }
}

__device__ __forceinline__ float dot4(v4f a, v4f b) {
    return a.x * b.x + a.y * b.y + a.z * b.z + a.w * b.w;
}

#define NTLOAD(p) __builtin_nontemporal_load(p)

// ---------------------------------------------------------------------------
// R3's proven fused stream, byte-identical structure: one wave per row-PAIR
// (grid-stride), 8 NT float4 loads in flight, reg-psi, dot+nrm butterfly,
// lane-0 top-5 insert. ONLY change vs R3: grid = 3200 blocks (12800 waves,
// exactly 5 pairs/wave) to test request-level-parallelism scaling.
// Assumes D == 1024 (256 float4/row).
// ---------------------------------------------------------------------------
__global__ __launch_bounds__(256) void sim_top_kernel(const v4f* __restrict__ vocab,
                                                      const v4f* __restrict__ psi4,
                                                      float* __restrict__ cand_v,
                                                      int* __restrict__ cand_i,
                                                      int V) {
    __shared__ float wvs[4 * TOPK];
    __shared__ int   wis[4 * TOPK];
    const int tid  = threadIdx.x;
    const int lane = tid & 63;
    const int wave = tid >> 6;
    const int wavesPerBlock = blockDim.x >> 6;
    const int gwave  = blockIdx.x * wavesPerBlock + wave;
    const int nwaves = gridDim.x * wavesPerBlock;

    // psi fragments in registers: 64 lanes x 4 chunks = all 256 float4 of psi.
    const v4f p0 = psi4[lane];
    const v4f p1 = psi4[64 + lane];
    const v4f p2 = psi4[128 + lane];
    const v4f p3 = psi4[192 + lane];

    // wave-redundant ||psi||^2 -> scale (identical add order in every wave)
    float ps = dot4(p0, p0) + dot4(p1, p1) + dot4(p2, p2) + dot4(p3, p3);
    for (int off = 32; off > 0; off >>= 1) ps += __shfl_xor(ps, off);
    const float scale = 1.0f / (sqrtf(ps) + EPS);

    float tv[TOPK]; int ti[TOPK];
#pragma unroll
    for (int j = 0; j < TOPK; ++j) { tv[j] = -INFINITY; ti[j] = INT_MAX; }

    const int NP = V >> 1;  // contiguous row pairs
    for (int p = gwave; p < NP; p += nwaves) {
        const v4f* ra = vocab + (size_t)(2 * p) * 256;
        v4f a0 = NTLOAD(ra + lane);
        v4f a1 = NTLOAD(ra + 64 + lane);
        v4f a2 = NTLOAD(ra + 128 + lane);
        v4f a3 = NTLOAD(ra + 192 + lane);
        v4f b0 = NTLOAD(ra + 256 + lane);
        v4f b1 = NTLOAD(ra + 320 + lane);
        v4f b2 = NTLOAD(ra + 384 + lane);
        v4f b3 = NTLOAD(ra + 448 + lane);

        float dotA = dot4(a0, p0) + dot4(a1, p1) + dot4(a2, p2) + dot4(a3, p3);
        float nrmA = dot4(a0, a0) + dot4(a1, a1) + dot4(a2, a2) + dot4(a3, a3);
        float dotB = dot4(b0, p0) + dot4(b1, p1) + dot4(b2, p2) + dot4(b3, p3);
        float nrmB = dot4(b0, b0) + dot4(b1, b1) + dot4(b2, b2) + dot4(b3, b3);

        for (int off = 32; off > 0; off >>= 1) {
            dotA += __shfl_xor(dotA, off);
            nrmA += __shfl_xor(nrmA, off);
            dotB += __shfl_xor(dotB, off);
            nrmB += __shfl_xor(nrmB, off);
        }
        if (lane == 0) {
            insert_top(tv, ti, dotA * scale / (sqrtf(nrmA) + EPS), 2 * p);
            insert_top(tv, ti, dotB * scale / (sqrtf(nrmB) + EPS), 2 * p + 1);
        }
    }

    // odd-V tail (not hit for V=128000)
    if ((V & 1) && gwave == 0) {
        const int row = V - 1;
        const v4f* ra = vocab + (size_t)row * 256;
        v4f a0 = ra[lane], a1 = ra[64 + lane], a2 = ra[128 + lane], a3 = ra[192 + lane];
        float dotA = dot4(a0, p0) + dot4(a1, p1) + dot4(a2, p2) + dot4(a3, p3);
        float nrmA = dot4(a0, a0) + dot4(a1, a1) + dot4(a2, a2) + dot4(a3, a3);
        for (int off = 32; off > 0; off >>= 1) {
            dotA += __shfl_xor(dotA, off);
            nrmA += __shfl_xor(nrmA, off);
        }
        if (lane == 0) insert_top(tv, ti, dotA * scale / (sqrtf(nrmA) + EPS), row);
    }

    if (lane == 0) {
#pragma unroll
        for (int j = 0; j < TOPK; ++j) { wvs[wave * TOPK + j] = tv[j]; wis[wave * TOPK + j] = ti[j]; }
    }
    __syncthreads();
    if (tid == 0) {
        float bv[TOPK]; int bi[TOPK];
#pragma unroll
        for (int j = 0; j < TOPK; ++j) { bv[j] = -INFINITY; bi[j] = INT_MAX; }
        for (int e = 0; e < wavesPerBlock * TOPK; ++e) insert_top(bv, bi, wvs[e], wis[e]);
#pragma unroll
        for (int j = 0; j < TOPK; ++j) {
            cand_v[blockIdx.x * TOPK + j] = bv[j];
            cand_i[blockIdx.x * TOPK + j] = bi[j];
        }
    }
}

// ---------------------------------------------------------------------------
// Reduce NC candidates -> global top-K. Single block; per-thread register
// top-5 -> wave butterfly merge -> LDS -> thread-0 final merge.
// out[0..K-1] = scores, out[K..2K-1] = indices (as float).
// ---------------------------------------------------------------------------
__global__ __launch_bounds__(1024) void topk_reduce_kernel(const float* __restrict__ cand_v,
                                                           const int* __restrict__ cand_i,
                                                           int NC, int K,
                                                           float* __restrict__ out) {
    __shared__ float wvs[16 * TOPK];
    __shared__ int   wis[16 * TOPK];
    const int tid = threadIdx.x;
    const int lane = tid & 63, wave = tid >> 6;
    const int nwaves = blockDim.x >> 6;

    float sv[TOPK]; int si[TOPK];
#pragma unroll
    for (int j = 0; j < TOPK; ++j) { sv[j] = -INFINITY; si[j] = INT_MAX; }

    for (int i = tid; i < NC; i += blockDim.x) insert_top(sv, si, cand_v[i], cand_i[i]);

    for (int step = 1; step < 64; step <<= 1) {
        float ov[TOPK]; int oi[TOPK];
#pragma unroll
        for (int j = 0; j < TOPK; ++j) {
            ov[j] = __shfl_xor(sv[j], step);
            oi[j] = __shfl_xor(si[j], step);
        }
#pragma unroll
        for (int j = 0; j < TOPK; ++j) insert_top(sv, si, ov[j], oi[j]);
    }

    if (lane == 0) {
#pragma unroll
        for (int j = 0; j < TOPK; ++j) { wvs[wave * TOPK + j] = sv[j]; wis[wave * TOPK + j] = si[j]; }
    }
    __syncthreads();
    if (tid == 0) {
        float bv[TOPK]; int bi[TOPK];
#pragma unroll
        for (int j = 0; j < TOPK; ++j) { bv[j] = -INFINITY; bi[j] = INT_MAX; }
        for (int e = 0; e < nwaves * TOPK; ++e) insert_top(bv, bi, wvs[e], wis[e]);
        for (int k = 0; k < K && k < TOPK; ++k) {
            out[k]     = bv[k];
            out[K + k] = (float)bi[k];
        }
    }
}

extern "C" void kernel_launch(void* const* d_in, const int* in_sizes, int n_in,
                              void* d_out, int out_size, void* d_ws, size_t ws_size,
                              hipStream_t stream) {
    const float* psi   = (const float*)d_in[0];
    const float* vocab = (const float*)d_in[1];
    const int D = in_sizes[0];           // 1024 (kernel assumes this)
    const int V = in_sizes[1] / D;       // 128000
    const int K = out_size / 2;          // 5
    (void)D;

    // 3200 blocks -> 12800 waves; 64000 pairs / 12800 = exactly 5 pairs/wave
    const int blocks = 3200;
    const int NC = blocks * TOPK;        // 16000 candidates

    float* cand_v = (float*)d_ws;
    int*   cand_i = (int*)((float*)d_ws + NC);

    sim_top_kernel<<<blocks, 256, 0, stream>>>((const v4f*)vocab, (const v4f*)psi,
                                               cand_v, cand_i, V);

    topk_reduce_kernel<<<1, 1024, 0, stream>>>(cand_v, cand_i, NC, K, (float*)d_out);
}

// Round 11
// 111.384 us; speedup vs baseline: 1.6284x; 1.0551x over previous
//
#include <hip/hip_runtime.h>
#include <math.h>
#include <limits.h>

#define EPS  1e-9f
#define TOPK 5

typedef float v4f __attribute__((ext_vector_type(4)));

// strict total order: higher val wins; on equal val, lower index wins
__device__ __forceinline__ bool better(float av, int ai, float bv, int bi) {
    return (av > bv) || (av == bv && ai < bi);
}

// insert (v,idx) into desc-sorted top-TOPK register arrays.
// Fully unrolled, all indices compile-time after unroll (no scratch).
__device__ __forceinline__ void insert_top(float sv[TOPK], int si[TOPK], float v, int idx) {
    if (!better(v, idx, sv[TOPK - 1], si[TOPK - 1])) return;
    sv[TOPK - 1] = v; si[TOPK - 1] = idx;
#pragma unroll
    for (int j = TOPK - 1; j > 0; --j) {
        if (better(sv[j], si[j], sv[j - 1], si[j - 1])) {
            float tv = sv[j]; sv[j] = sv[j - 1]; sv[j - 1] = tv;
            int   ti = si[j]; si[j] = si[j - 1]; si[j - 1] = ti;
        }
    }
}

__device__ __forceinline__ float dot4(v4f a, v4f b) {
    return a.x * b.x + a.y * b.y + a.z * b.z + a.w * b.w;
}

#define NTLOAD(p) __builtin_nontemporal_load(p)

// ---------------------------------------------------------------------------
// BEST-KNOWN CONFIG (R3, 113.7 us): one wave per row-PAIR grid-stride,
// 8 nontemporal float4 loads in flight (read-once 512MB stream, no cache
// allocation), psi in 16 VGPRs, dot+nrm butterfly, lane-0 top-5 insert,
// 2000 blocks (8000 waves x exactly 8 pairs). Assumes D == 1024.
// Tested-and-rejected: contiguous-per-wave (-8us), 2-deep pipeline (0),
// occupancy cap (spills), last-block fused reduce (-68us), 3200 blocks (-4us).
// ---------------------------------------------------------------------------
__global__ __launch_bounds__(256) void sim_top_kernel(const v4f* __restrict__ vocab,
                                                      const v4f* __restrict__ psi4,
                                                      float* __restrict__ cand_v,
                                                      int* __restrict__ cand_i,
                                                      int V) {
    __shared__ float wvs[4 * TOPK];
    __shared__ int   wis[4 * TOPK];
    const int tid  = threadIdx.x;
    const int lane = tid & 63;
    const int wave = tid >> 6;
    const int wavesPerBlock = blockDim.x >> 6;
    const int gwave  = blockIdx.x * wavesPerBlock + wave;
    const int nwaves = gridDim.x * wavesPerBlock;

    // psi fragments in registers: 64 lanes x 4 chunks = all 256 float4 of psi.
    const v4f p0 = psi4[lane];
    const v4f p1 = psi4[64 + lane];
    const v4f p2 = psi4[128 + lane];
    const v4f p3 = psi4[192 + lane];

    // wave-redundant ||psi||^2 -> scale (identical add order in every wave)
    float ps = dot4(p0, p0) + dot4(p1, p1) + dot4(p2, p2) + dot4(p3, p3);
    for (int off = 32; off > 0; off >>= 1) ps += __shfl_xor(ps, off);
    const float scale = 1.0f / (sqrtf(ps) + EPS);

    float tv[TOPK]; int ti[TOPK];
#pragma unroll
    for (int j = 0; j < TOPK; ++j) { tv[j] = -INFINITY; ti[j] = INT_MAX; }

    const int NP = V >> 1;  // contiguous row pairs
    for (int p = gwave; p < NP; p += nwaves) {
        const v4f* ra = vocab + (size_t)(2 * p) * 256;
        v4f a0 = NTLOAD(ra + lane);
        v4f a1 = NTLOAD(ra + 64 + lane);
        v4f a2 = NTLOAD(ra + 128 + lane);
        v4f a3 = NTLOAD(ra + 192 + lane);
        v4f b0 = NTLOAD(ra + 256 + lane);
        v4f b1 = NTLOAD(ra + 320 + lane);
        v4f b2 = NTLOAD(ra + 384 + lane);
        v4f b3 = NTLOAD(ra + 448 + lane);

        float dotA = dot4(a0, p0) + dot4(a1, p1) + dot4(a2, p2) + dot4(a3, p3);
        float nrmA = dot4(a0, a0) + dot4(a1, a1) + dot4(a2, a2) + dot4(a3, a3);
        float dotB = dot4(b0, p0) + dot4(b1, p1) + dot4(b2, p2) + dot4(b3, p3);
        float nrmB = dot4(b0, b0) + dot4(b1, b1) + dot4(b2, b2) + dot4(b3, b3);

        for (int off = 32; off > 0; off >>= 1) {
            dotA += __shfl_xor(dotA, off);
            nrmA += __shfl_xor(nrmA, off);
            dotB += __shfl_xor(dotB, off);
            nrmB += __shfl_xor(nrmB, off);
        }
        if (lane == 0) {
            insert_top(tv, ti, dotA * scale / (sqrtf(nrmA) + EPS), 2 * p);
            insert_top(tv, ti, dotB * scale / (sqrtf(nrmB) + EPS), 2 * p + 1);
        }
    }

    // odd-V tail (not hit for V=128000)
    if ((V & 1) && gwave == 0) {
        const int row = V - 1;
        const v4f* ra = vocab + (size_t)row * 256;
        v4f a0 = ra[lane], a1 = ra[64 + lane], a2 = ra[128 + lane], a3 = ra[192 + lane];
        float dotA = dot4(a0, p0) + dot4(a1, p1) + dot4(a2, p2) + dot4(a3, p3);
        float nrmA = dot4(a0, a0) + dot4(a1, a1) + dot4(a2, a2) + dot4(a3, a3);
        for (int off = 32; off > 0; off >>= 1) {
            dotA += __shfl_xor(dotA, off);
            nrmA += __shfl_xor(nrmA, off);
        }
        if (lane == 0) insert_top(tv, ti, dotA * scale / (sqrtf(nrmA) + EPS), row);
    }

    if (lane == 0) {
#pragma unroll
        for (int j = 0; j < TOPK; ++j) { wvs[wave * TOPK + j] = tv[j]; wis[wave * TOPK + j] = ti[j]; }
    }
    __syncthreads();
    if (tid == 0) {
        float bv[TOPK]; int bi[TOPK];
#pragma unroll
        for (int j = 0; j < TOPK; ++j) { bv[j] = -INFINITY; bi[j] = INT_MAX; }
        for (int e = 0; e < wavesPerBlock * TOPK; ++e) insert_top(bv, bi, wvs[e], wis[e]);
#pragma unroll
        for (int j = 0; j < TOPK; ++j) {
            cand_v[blockIdx.x * TOPK + j] = bv[j];
            cand_i[blockIdx.x * TOPK + j] = bi[j];
        }
    }
}

// ---------------------------------------------------------------------------
// Reduce NC candidates -> global top-K. Single block, 512 threads (8 waves:
// 40-entry thread-0 serial merge instead of 80 at 1024). Per-thread register
// top-5 -> wave butterfly merge -> LDS -> thread-0 final merge.
// out[0..K-1] = scores, out[K..2K-1] = indices (as float).
// ---------------------------------------------------------------------------
__global__ __launch_bounds__(512) void topk_reduce_kernel(const float* __restrict__ cand_v,
                                                          const int* __restrict__ cand_i,
                                                          int NC, int K,
                                                          float* __restrict__ out) {
    __shared__ float wvs[8 * TOPK];
    __shared__ int   wis[8 * TOPK];
    const int tid = threadIdx.x;
    const int lane = tid & 63, wave = tid >> 6;
    const int nwaves = blockDim.x >> 6;

    float sv[TOPK]; int si[TOPK];
#pragma unroll
    for (int j = 0; j < TOPK; ++j) { sv[j] = -INFINITY; si[j] = INT_MAX; }

    for (int i = tid; i < NC; i += blockDim.x) insert_top(sv, si, cand_v[i], cand_i[i]);

    for (int step = 1; step < 64; step <<= 1) {
        float ov[TOPK]; int oi[TOPK];
#pragma unroll
        for (int j = 0; j < TOPK; ++j) {
            ov[j] = __shfl_xor(sv[j], step);
            oi[j] = __shfl_xor(si[j], step);
        }
#pragma unroll
        for (int j = 0; j < TOPK; ++j) insert_top(sv, si, ov[j], oi[j]);
    }

    if (lane == 0) {
#pragma unroll
        for (int j = 0; j < TOPK; ++j) { wvs[wave * TOPK + j] = sv[j]; wis[wave * TOPK + j] = si[j]; }
    }
    __syncthreads();
    if (tid == 0) {
        float bv[TOPK]; int bi[TOPK];
#pragma unroll
        for (int j = 0; j < TOPK; ++j) { bv[j] = -INFINITY; bi[j] = INT_MAX; }
        for (int e = 0; e < nwaves * TOPK; ++e) insert_top(bv, bi, wvs[e], wis[e]);
        for (int k = 0; k < K && k < TOPK; ++k) {
            out[k]     = bv[k];
            out[K + k] = (float)bi[k];
        }
    }
}

extern "C" void kernel_launch(void* const* d_in, const int* in_sizes, int n_in,
                              void* d_out, int out_size, void* d_ws, size_t ws_size,
                              hipStream_t stream) {
    const float* psi   = (const float*)d_in[0];
    const float* vocab = (const float*)d_in[1];
    const int D = in_sizes[0];           // 1024 (kernel assumes this)
    const int V = in_sizes[1] / D;       // 128000
    const int K = out_size / 2;          // 5
    (void)D;

    // 2000 blocks -> 8000 waves; 64000 pairs / 8000 = exactly 8 pairs/wave
    const int blocks = 2000;
    const int NC = blocks * TOPK;        // 10000 candidates

    float* cand_v = (float*)d_ws;
    int*   cand_i = (int*)((float*)d_ws + NC);

    sim_top_kernel<<<blocks, 256, 0, stream>>>((const v4f*)vocab, (const v4f*)psi,
                                               cand_v, cand_i, V);

    topk_reduce_kernel<<<1, 512, 0, stream>>>(cand_v, cand_i, NC, K, (float*)d_out);
}